// Round 12
// baseline (308.908 us; speedup 1.0000x reference)
//
#include <hip/hip_runtime.h>

#define N_NODES 50000
#define N_EDGES 800000
#define D 128
#define BN_EPS 1e-5f

#define NBUCK 391        // ceil(N_NODES / 128)
#define BSHIFT 7         // 128 nodes per bucket
#define CAP 2560         // per-bucket region capacity (mean 2048, sd 45 -> +11 sigma)
#define S1_BLOCKS 256
#define EPB 3125         // edges per scatter block (256*3125 == 800000)
#define CVT_BLOCKS 6250  // N_NODES*D/4 / 256
#define PACK_BLOCKS 384  // 3*32768 / 256
#define NREP 4           // stats replicas (fold is per-BLOCK)
#define NSLICE 16        // src-slice bins (1 MB slices)
#define SSHIFT 12        // 4096 nodes/slice = 1 MB of bf16 rows

typedef __attribute__((ext_vector_type(8))) short bf16x8;
typedef __attribute__((ext_vector_type(4))) float f32x4;
typedef __attribute__((ext_vector_type(2))) float f32x2;

// fp32 -> bf16 (RNE)
__device__ inline unsigned short f2bf(float f) {
    unsigned int u = __float_as_uint(f);
    u = (u + 0x7FFF + ((u >> 16) & 1)) >> 16;
    return (unsigned short)u;
}

__device__ inline float bf2f(unsigned short b) {
    return __uint_as_float(((unsigned)b) << 16);
}

__device__ __forceinline__ void acc_plain(f32x2* a, uint4 v) {
    unsigned w[4] = {v.x, v.y, v.z, v.w};
#pragma unroll
    for (int p = 0; p < 4; p++) {
        f32x2 f;
        f.x = __uint_as_float(w[p] << 16);          // even col
        f.y = __uint_as_float(w[p] & 0xffff0000u);  // odd col
        a[p] += f;
    }
}

// per-edge BN+ReLU accumulate: sc/sh are per-lane registers
__device__ __forceinline__ void acc_bn(f32x2* a, uint4 v, const float* sc, const float* sh) {
    unsigned w[4] = {v.x, v.y, v.z, v.w};
#pragma unroll
    for (int p = 0; p < 4; p++) {
        float lo = __uint_as_float(w[p] << 16);
        float hi = __uint_as_float(w[p] & 0xffff0000u);
        a[p].x += fmaxf(lo * sc[2 * p]     + sh[2 * p],     0.f);
        a[p].y += fmaxf(hi * sc[2 * p + 1] + sh[2 * p + 1], 0.f);
    }
}

// ---------------- fused prep: convert_x | pack_w | zero stats+counters ----------
// Round-21: the edge-histogram phase is GONE — the scatter now uses global
// atomic counters into fixed-capacity bucket regions (no pre-counting needed).

__global__ void fused_prep(const float* __restrict__ x, unsigned short* __restrict__ x16,
                           const float* __restrict__ Ws0, const float* __restrict__ Wn0,
                           const float* __restrict__ Ws1, const float* __restrict__ Wn1,
                           const float* __restrict__ Ws2, const float* __restrict__ Wn2,
                           unsigned short* __restrict__ Wf, float* __restrict__ statsg,
                           int* __restrict__ cntg) {
    const int bid = blockIdx.x, t = threadIdx.x;

    if (bid < CVT_BLOCKS) {
        int idx = bid * 256 + t;
        float4 v = ((const float4*)x)[idx];
        ushort4 o;
        o.x = f2bf(v.x); o.y = f2bf(v.y); o.z = f2bf(v.z); o.w = f2bf(v.w);
        ((ushort4*)x16)[idx] = o;
    } else {
        if (bid == CVT_BLOCKS) {   // zero BN stats + bucket counters
            for (int i = t; i < 2 * NREP * 256; i += 256) statsg[i] = 0.f;
            for (int i = t; i < NBUCK * 16; i += 256) cntg[i] = 0;
        }
        // pack weights into MFMA B-fragment order:
        // Wf[layer][kt(8)][nt(8)][lane(64)][j(8)], lane l holds
        // B[kt*32 + 8*(l>>4) + j][nt*16 + (l&15)].
        int idx = (bid - CVT_BLOCKS) * 256 + t;
        if (idx < 3 * 32768) {
            int layer = idx >> 15;
            int rem = idx & 32767;
            int kt = rem >> 12;
            int nt = (rem >> 9) & 7;
            int lane = (rem >> 3) & 63;
            int j = rem & 7;
            int k = kt * 32 + (lane >> 4) * 8 + j;
            int n = nt * 16 + (lane & 15);
            const float* Wsrc;
            if (layer == 0) Wsrc = (k < 128) ? Ws0 : Wn0;
            else if (layer == 1) Wsrc = (k < 128) ? Ws1 : Wn1;
            else Wsrc = (k < 128) ? Ws2 : Wn2;
            Wf[idx] = f2bf(Wsrc[(k & 127) * D + n]);
        }
    }
}

// ---------------- S3: atomic scatter into fixed-capacity bucket regions ----------
// Round-21: replaces hist + s2a + LDS-base scatter. Counters padded to 64 B
// (16 ints) so the 391 atomic chains serialize only per-address (~2046 ops
// x ~3cy = 2.6 us, parallel across buckets). Edge order within a bucket is
// nondeterministic — s4 re-sorts by (node, slice), so semantics unchanged.

__global__ void s3_scatter(const int* __restrict__ src, const int* __restrict__ dst,
                           int* __restrict__ cnt, unsigned int* __restrict__ rec) {
    int t = threadIdx.x;
    int e0 = blockIdx.x * EPB;
    for (int i = 0; i < 13; i++) {
        int k = t + i * 256;
        if (k < EPB) {
            int e = e0 + k;
            int d = dst[e];
            int bkt = d >> BSHIFT;
            int p = atomicAdd(&cnt[bkt * 16], 1);
            if (p < CAP)
                rec[(size_t)bkt * CAP + p] = ((unsigned)(d & 127) << 16) | (unsigned)src[e];
        }
    }
}

// ---------------- S4: per-bucket counting sort -> CSR + degrees ----------------
// Bucket b's records live in [b*CAP, b*CAP + cnt[b]); CSR stays in the same
// padded region (offsets[node] = b*CAP + excl — nothing needs global
// contiguity). Slice key = (dst&127, src>>12): 1 MB src slices; 2048-bin sort.

__global__ void s4_build(const unsigned int* __restrict__ rec, const int* __restrict__ cnt,
                         unsigned short* __restrict__ csr, int* __restrict__ degi,
                         int* __restrict__ offsets, float* __restrict__ inv_deg) {
    __shared__ int cnt2[128 * NSLICE];
    __shared__ int exc[128 * NSLICE];
    __shared__ int lcur[128 * NSLICE];
    __shared__ int ls[256];
    int b = blockIdx.x, t = threadIdx.x;
    int start = b * CAP;
    int count = cnt[b * 16];
    if (count > CAP) count = CAP;
    int end = start + count;

    for (int i = t; i < 128 * NSLICE; i += 256) cnt2[i] = 0;
    __syncthreads();
    for (int e = start + t; e < end; e += 256) {
        unsigned r = rec[e];
        int key = ((r >> 16) << 4) | ((r & 0xFFFFu) >> SSHIFT);
        atomicAdd(&cnt2[key], 1);
    }
    __syncthreads();

    // 2048-bin exclusive scan: 8 bins/thread (registers, fully unrolled)
    int cs[8];
    int sum8 = 0;
#pragma unroll
    for (int j = 0; j < 8; j++) { cs[j] = cnt2[8 * t + j]; sum8 += cs[j]; }
    ls[t] = sum8;
    __syncthreads();
    for (int off = 1; off < 256; off <<= 1) {
        int x = (t >= off) ? ls[t - off] : 0;
        __syncthreads();
        ls[t] += x;
        __syncthreads();
    }
    int run = ls[t] - sum8;
#pragma unroll
    for (int j = 0; j < 8; j++) {
        exc[8 * t + j] = run;
        lcur[8 * t + j] = start + run;
        run += cs[j];
    }
    __syncthreads();

    if (t < 128) {
        int node = (b << BSHIFT) + t;
        int e0 = exc[t * NSLICE];
        int e1 = (t == 127) ? count : exc[(t + 1) * NSLICE];
        int v = e1 - e0;
        if (node < N_NODES) {
            degi[node] = v;
            offsets[node] = start + e0;
            inv_deg[node] = 1.0f / (float)max(v, 1);
        }
    }
    __syncthreads();
    for (int e = start + t; e < end; e += 256) {
        unsigned r = rec[e];
        int key = ((r >> 16) << 4) | ((r & 0xFFFFu) >> SSHIFT);
        int p = atomicAdd(&lcur[key], 1);
        csr[p] = (unsigned short)(r & 0xFFFFu);
    }
}

// ---------------- mean aggregation with optional fused BN+ReLU ----------------
// Per-block BN fold into LDS then 16 regs/lane; batched csr indices broadcast
// via __shfl (no per-edge index hop); 4-deep row-gather pipeline.

#define GROW(r) (*(const uint4*)(hb + ((size_t)(r) << 7)))
#define ROWIDX(k) __shfl((int)((k) < 16 ? cb0 : ((k) < 32 ? cb1 : cb2)), (k) & 15, 16)

__global__ void aggregate16(const unsigned short* __restrict__ h16,
                            const unsigned short* __restrict__ csr, const int* __restrict__ offsets,
                            const int* __restrict__ degi, const float* __restrict__ inv_deg,
                            unsigned short* __restrict__ mean16,
                            const float* __restrict__ statsIn,
                            const float* __restrict__ gammaIn, const float* __restrict__ betaIn) {
    __shared__ float lsc[128], lsh[128];
    int t = threadIdx.x;
    if (statsIn) {
        if (t < 128) {
            const float invN = 1.0f / (float)N_NODES;
            float s = 0.f, q = 0.f;
#pragma unroll
            for (int r = 0; r < NREP; r++) {
                s += statsIn[r * 256 + t];
                q += statsIn[r * 256 + 128 + t];
            }
            float m = s * invN;
            float var = q * invN - m * m;
            float scv = rsqrtf(var + BN_EPS) * gammaIn[t];
            lsc[t] = scv;
            lsh[t] = betaIn[t] - m * scv;
        }
        __syncthreads();
    }

    int node = blockIdx.x * 16 + (t >> 4);   // grid*16 == N_NODES exactly
    int c = t & 15;
    const unsigned short* hb = h16 + c * 8;
    int beg = offsets[node], n = degi[node];

    // batch-load up to 48 neighbor indices (lane c holds entries c, 16+c, 32+c)
    int ci = beg + c;
    int cmax = NBUCK * CAP - 1;
    unsigned cb0 = csr[min(ci, cmax)];
    unsigned cb1 = csr[min(ci + 16, cmax)];
    unsigned cb2 = csr[min(ci + 32, cmax)];

    f32x2 a[4];
#pragma unroll
    for (int j = 0; j < 4; j++) a[j] = (f32x2)(0.f);

    int nfast = n < 48 ? n : 48;
    int i = 0;
    if (statsIn) {
        float scv[8], shv[8];
#pragma unroll
        for (int j = 0; j < 8; j++) { scv[j] = lsc[c * 8 + j]; shv[j] = lsh[c * 8 + j]; }
        if (nfast >= 4) {
            uint4 v0 = GROW(ROWIDX(0)), v1 = GROW(ROWIDX(1));
            uint4 v2 = GROW(ROWIDX(2)), v3 = GROW(ROWIDX(3));
            for (i = 4; i + 3 < nfast; i += 4) {
                int r0 = ROWIDX(i), r1 = ROWIDX(i + 1), r2 = ROWIDX(i + 2), r3 = ROWIDX(i + 3);
                uint4 w0 = GROW(r0), w1 = GROW(r1), w2 = GROW(r2), w3 = GROW(r3);
                acc_bn(a, v0, scv, shv); acc_bn(a, v1, scv, shv);
                acc_bn(a, v2, scv, shv); acc_bn(a, v3, scv, shv);
                v0 = w0; v1 = w1; v2 = w2; v3 = w3;
            }
            acc_bn(a, v0, scv, shv); acc_bn(a, v1, scv, shv);
            acc_bn(a, v2, scv, shv); acc_bn(a, v3, scv, shv);
        }
        for (; i < nfast; i++) { uint4 v = GROW(ROWIDX(i)); acc_bn(a, v, scv, shv); }
        for (; i < n; i++) { int r = csr[beg + i]; uint4 v = GROW(r); acc_bn(a, v, scv, shv); }
    } else {
        if (nfast >= 4) {
            uint4 v0 = GROW(ROWIDX(0)), v1 = GROW(ROWIDX(1));
            uint4 v2 = GROW(ROWIDX(2)), v3 = GROW(ROWIDX(3));
            for (i = 4; i + 3 < nfast; i += 4) {
                int r0 = ROWIDX(i), r1 = ROWIDX(i + 1), r2 = ROWIDX(i + 2), r3 = ROWIDX(i + 3);
                uint4 w0 = GROW(r0), w1 = GROW(r1), w2 = GROW(r2), w3 = GROW(r3);
                acc_plain(a, v0); acc_plain(a, v1); acc_plain(a, v2); acc_plain(a, v3);
                v0 = w0; v1 = w1; v2 = w2; v3 = w3;
            }
            acc_plain(a, v0); acc_plain(a, v1); acc_plain(a, v2); acc_plain(a, v3);
        }
        for (; i < nfast; i++) { uint4 v = GROW(ROWIDX(i)); acc_plain(a, v); }
        for (; i < n; i++) { int r = csr[beg + i]; uint4 v = GROW(r); acc_plain(a, v); }
    }

    float w = inv_deg[node];
    uint4 o;
    o.x = ((unsigned)f2bf(a[0].y * w) << 16) | f2bf(a[0].x * w);
    o.y = ((unsigned)f2bf(a[1].y * w) << 16) | f2bf(a[1].x * w);
    o.z = ((unsigned)f2bf(a[2].y * w) << 16) | f2bf(a[2].x * w);
    o.w = ((unsigned)f2bf(a[3].y * w) << 16) | f2bf(a[3].x * w);
    *(uint4*)(mean16 + (size_t)node * D + c * 8) = o;
}

// ---------------- MFMA SAGE GEMM, M=128 tile + fused BN col-stats ----------------
// Each B-frag ds_read_b128 feeds TWO MFMAs (accA/accB) -> ds:MFMA balanced;
// Wf L2 refetch and block count halved vs M=64 (391 blocks).
// C/D layout (m89-verified): col = lane&15, row = (lane>>4)*4 + reg.

__global__ __launch_bounds__(256, 3) void sage_gemm(
    const unsigned short* __restrict__ h16, const unsigned short* __restrict__ mean16,
    const unsigned short* __restrict__ Wf, const float* __restrict__ bias,
    unsigned short* __restrict__ out16, float* __restrict__ outf,
    float* __restrict__ statsOut,
    const float* __restrict__ statsIn,
    const float* __restrict__ gammaIn, const float* __restrict__ betaIn) {
    __shared__ unsigned short sWf[16384];   // 32 KB: one K-half (4 kt x 8 nt x 64 x 8)
    __shared__ float sstat[256];
    __shared__ float lsc[128], lsh[128];
    const int t = threadIdx.x;
    const int lane = t & 63;
    const int m = lane & 15;
    const int quad = lane >> 4;
    const int wrow0 = blockIdx.x * 128 + (t >> 6) * 32;   // wave owns 32 rows

    int arowA = wrow0 + m;
    int arowB = wrow0 + 16 + m;
    if (arowA >= N_NODES) arowA = N_NODES - 1;
    if (arowB >= N_NODES) arowB = N_NODES - 1;

    // prefetch A-fragments for both M-tiles (4 self + 4 mean each)
    bf16x8 afrA[8], afrB[8];
#pragma unroll
    for (int kt = 0; kt < 4; kt++) {
        afrA[kt] = *(const bf16x8*)(h16 + (size_t)arowA * D + kt * 32 + quad * 8);
        afrB[kt] = *(const bf16x8*)(h16 + (size_t)arowB * D + kt * 32 + quad * 8);
    }
#pragma unroll
    for (int kt = 0; kt < 4; kt++) {
        afrA[4 + kt] = *(const bf16x8*)(mean16 + (size_t)arowA * D + kt * 32 + quad * 8);
        afrB[4 + kt] = *(const bf16x8*)(mean16 + (size_t)arowB * D + kt * 32 + quad * 8);
    }

    // fold BN table for self fragments (layers 1,2)
    if (statsIn && t < 128) {
        const float invN = 1.0f / (float)N_NODES;
        float s = 0.f, q = 0.f;
#pragma unroll
        for (int r = 0; r < NREP; r++) {
            s += statsIn[r * 256 + t];
            q += statsIn[r * 256 + 128 + t];
        }
        float m2 = s * invN;
        float var = q * invN - m2 * m2;
        float scv = rsqrtf(var + BN_EPS) * gammaIn[t];
        lsc[t] = scv;
        lsh[t] = betaIn[t] - m2 * scv;
    }

    // stage first weight half (kt 0-3)
    const uint4* W4 = (const uint4*)Wf;
    uint4* S4 = (uint4*)sWf;
#pragma unroll
    for (int i = 0; i < 8; i++) S4[i * 256 + t] = W4[i * 256 + t];
    if (statsOut) sstat[t] = 0.f;
    __syncthreads();

    // apply BN+ReLU to self fragments in-register
    if (statsIn) {
#pragma unroll
        for (int kt = 0; kt < 4; kt++) {
            int c0 = kt * 32 + quad * 8;
#pragma unroll
            for (int j = 0; j < 8; j++) {
                float vA = fmaxf(bf2f((unsigned short)afrA[kt][j]) * lsc[c0 + j] + lsh[c0 + j], 0.f);
                float vB = fmaxf(bf2f((unsigned short)afrB[kt][j]) * lsc[c0 + j] + lsh[c0 + j], 0.f);
                afrA[kt][j] = (short)f2bf(vA);
                afrB[kt][j] = (short)f2bf(vB);
            }
        }
    }

    f32x4 accA[8], accB[8];
#pragma unroll
    for (int i = 0; i < 8; i++) { accA[i] = (f32x4)(0.f); accB[i] = (f32x4)(0.f); }

#pragma unroll
    for (int kt = 0; kt < 4; kt++) {
#pragma unroll
        for (int nt = 0; nt < 8; nt++) {
            bf16x8 bf = *(const bf16x8*)(sWf + ((kt * 8 + nt) * 64 + lane) * 8);
            accA[nt] = __builtin_amdgcn_mfma_f32_16x16x32_bf16(afrA[kt], bf, accA[nt], 0, 0, 0);
            accB[nt] = __builtin_amdgcn_mfma_f32_16x16x32_bf16(afrB[kt], bf, accB[nt], 0, 0, 0);
        }
    }

    __syncthreads();   // all waves done with half 1 before overwrite
#pragma unroll
    for (int i = 0; i < 8; i++) S4[i * 256 + t] = W4[2048 + i * 256 + t];
    __syncthreads();

#pragma unroll
    for (int kt = 4; kt < 8; kt++) {
#pragma unroll
        for (int nt = 0; nt < 8; nt++) {
            bf16x8 bf = *(const bf16x8*)(sWf + (((kt - 4) * 8 + nt) * 64 + lane) * 8);
            accA[nt] = __builtin_amdgcn_mfma_f32_16x16x32_bf16(afrA[kt], bf, accA[nt], 0, 0, 0);
            accB[nt] = __builtin_amdgcn_mfma_f32_16x16x32_bf16(afrB[kt], bf, accB[nt], 0, 0, 0);
        }
    }

    const bool do16 = (out16 != nullptr);
#pragma unroll
    for (int nt = 0; nt < 8; nt++) {
        int cidx = nt * 16 + m;
        float bv = bias[cidx];
        float s = 0.f, q = 0.f;
#pragma unroll
        for (int reg = 0; reg < 4; reg++) {
            int rA = wrow0 + quad * 4 + reg;
            float vA = accA[nt][reg] + bv;
            if (rA < N_NODES) {
                if (do16) out16[(size_t)rA * D + cidx] = f2bf(vA);
                else      outf[(size_t)rA * D + cidx] = vA;
                s += vA; q += vA * vA;
            }
            int rB = wrow0 + 16 + quad * 4 + reg;
            float vB = accB[nt][reg] + bv;
            if (rB < N_NODES) {
                if (do16) out16[(size_t)rB * D + cidx] = f2bf(vB);
                else      outf[(size_t)rB * D + cidx] = vB;
                s += vB; q += vB * vB;
            }
        }
        if (statsOut) {
            s += __shfl_xor(s, 16); s += __shfl_xor(s, 32);
            q += __shfl_xor(q, 16); q += __shfl_xor(q, 32);
            if (quad == 0) {
                atomicAdd(&sstat[cidx], s);
                atomicAdd(&sstat[128 + cidx], q);
            }
        }
    }
    if (statsOut) {
        __syncthreads();
        atomicAdd(&statsOut[(blockIdx.x & (NREP - 1)) * 256 + t], sstat[t]);
    }
}

// ---------------- launch ----------------

extern "C" void kernel_launch(void* const* d_in, const int* in_sizes, int n_in,
                              void* d_out, int out_size, void* d_ws, size_t ws_size,
                              hipStream_t stream) {
    const float* x   = (const float*)d_in[0];
    const int* src   = (const int*)d_in[1];
    const int* dst   = (const int*)d_in[2];
    const float* Ws0 = (const float*)d_in[3];
    const float* Wn0 = (const float*)d_in[4];
    const float* b0  = (const float*)d_in[5];
    const float* Ws1 = (const float*)d_in[6];
    const float* Wn1 = (const float*)d_in[7];
    const float* b1  = (const float*)d_in[8];
    const float* Ws2 = (const float*)d_in[9];
    const float* Wn2 = (const float*)d_in[10];
    const float* b2  = (const float*)d_in[11];
    const float* g0  = (const float*)d_in[12];
    const float* be0 = (const float*)d_in[13];
    const float* g1  = (const float*)d_in[14];
    const float* be1 = (const float*)d_in[15];

    char* base = (char*)d_ws;
    size_t NND = (size_t)N_NODES * D;
    unsigned short* X16    = (unsigned short*)base;                 // 12.8 MB
    unsigned short* H16    = (unsigned short*)(base + NND * 2);     // 12.8 MB
    unsigned short* mean16 = (unsigned short*)(base + 2 * NND * 2); // 12.8 MB
    char* p = base + 6 * NND;
    unsigned short* Wf = (unsigned short*)p;  p += 3 * 32768 * 2;                  // 192 KB
    int* cnt           = (int*)p;             p += NBUCK * 16 * 4;                 // 25 KB (64B-padded)
    unsigned int* rec  = (unsigned int*)p;    p += (size_t)NBUCK * CAP * 4;        // 4.0 MB
    unsigned short* csr = (unsigned short*)p; p += (size_t)NBUCK * CAP * 2;        // 2.0 MB
    int* degi    = (int*)p;                   p += N_NODES * 4;
    int* offsets = (int*)p;                   p += N_NODES * 4;
    float* inv_deg = (float*)p;               p += N_NODES * 4;
    float* stats   = (float*)p;               p += 2 * NREP * 256 * 4;  // replicated
    float* stats0 = stats, *stats1 = stats + NREP * 256;

    // prep: feature convert + weight pack + zero stats/counters
    fused_prep<<<CVT_BLOCKS + PACK_BLOCKS, 256, 0, stream>>>(
        x, X16, Ws0, Wn0, Ws1, Wn1, Ws2, Wn2, Wf, stats, cnt);
    // CSR build: 2 kernels (atomic scatter into fixed-capacity regions, then
    // per-bucket (node, slice) counting sort)
    s3_scatter<<<S1_BLOCKS, 256, 0, stream>>>(src, dst, cnt, rec);
    s4_build<<<NBUCK, 256, 0, stream>>>(rec, cnt, csr, degi, offsets, inv_deg);

    const int AGG_B = (N_NODES + 15) / 16;     // 3125
    const int GEMM_B = (N_NODES + 127) / 128;  // 391

    // Layer 0: X16 (no BN) -> H16 raw + stats0
    aggregate16<<<AGG_B, 256, 0, stream>>>(X16, csr, offsets, degi, inv_deg, mean16,
                                           nullptr, nullptr, nullptr);
    sage_gemm<<<GEMM_B, 256, 0, stream>>>(X16, mean16, Wf, b0, H16, nullptr,
                                          stats0, nullptr, nullptr, nullptr);

    // Layer 1: consumers apply bn0+relu to H16 raw -> X16 raw + stats1
    aggregate16<<<AGG_B, 256, 0, stream>>>(H16, csr, offsets, degi, inv_deg, mean16,
                                           stats0, g0, be0);
    sage_gemm<<<GEMM_B, 256, 0, stream>>>(H16, mean16, Wf + 32768, b1, X16, nullptr,
                                          stats1, stats0, g0, be0);

    // Layer 2: consumers apply bn1+relu to X16 raw -> d_out fp32
    aggregate16<<<AGG_B, 256, 0, stream>>>(X16, csr, offsets, degi, inv_deg, mean16,
                                           stats1, g1, be1);
    sage_gemm<<<GEMM_B, 256, 0, stream>>>(X16, mean16, Wf + 65536, b2, nullptr,
                                          (float*)d_out, nullptr, stats1, g1, be1);
}

// Round 14
// 277.915 us; speedup vs baseline: 1.1115x; 1.1115x over previous
//
#include <hip/hip_runtime.h>

#define N_NODES 50000
#define N_EDGES 800000
#define D 128
#define BN_EPS 1e-5f

#define NBUCK 391        // ceil(N_NODES / 128)
#define BSHIFT 7         // 128 nodes per bucket
#define S1_BLOCKS 256
#define EPB 3125         // edges per histogram/scatter block (256*3125 == 800000)
#define CVT_BLOCKS 6250  // N_NODES*D/4 / 256
#define PACK_BLOCKS 384  // 3*32768 / 256
#define NREP 4           // stats replicas (fold is per-BLOCK)
#define NSLICE 16        // src-slice bins (1 MB slices)
#define SSHIFT 12        // 4096 nodes/slice = 1 MB of bf16 rows

typedef __attribute__((ext_vector_type(8))) short bf16x8;
typedef __attribute__((ext_vector_type(4))) float f32x4;
typedef __attribute__((ext_vector_type(2))) float f32x2;

// fp32 -> bf16 (RNE)
__device__ inline unsigned short f2bf(float f) {
    unsigned int u = __float_as_uint(f);
    u = (u + 0x7FFF + ((u >> 16) & 1)) >> 16;
    return (unsigned short)u;
}

__device__ inline float bf2f(unsigned short b) {
    return __uint_as_float(((unsigned)b) << 16);
}

__device__ __forceinline__ void acc_plain(f32x2* a, uint4 v) {
    unsigned w[4] = {v.x, v.y, v.z, v.w};
#pragma unroll
    for (int p = 0; p < 4; p++) {
        f32x2 f;
        f.x = __uint_as_float(w[p] << 16);          // even col
        f.y = __uint_as_float(w[p] & 0xffff0000u);  // odd col
        a[p] += f;
    }
}

// per-edge BN+ReLU accumulate: sc/sh are per-lane registers
__device__ __forceinline__ void acc_bn(f32x2* a, uint4 v, const float* sc, const float* sh) {
    unsigned w[4] = {v.x, v.y, v.z, v.w};
#pragma unroll
    for (int p = 0; p < 4; p++) {
        float lo = __uint_as_float(w[p] << 16);
        float hi = __uint_as_float(w[p] & 0xffff0000u);
        a[p].x += fmaxf(lo * sc[2 * p]     + sh[2 * p],     0.f);
        a[p].y += fmaxf(hi * sc[2 * p + 1] + sh[2 * p + 1], 0.f);
    }
}

// ---------------- fused prep: convert_x | edge histogram | pack_w (+zero) ----------
// Round-12 lesson: global-atomic scatter = 46us (cross-XCD same-line atomics run
// at coherence-round-trip cost, ~50cy/op). The LDS-histogram pipeline stays.

__global__ void fused_prep(const float* __restrict__ x, unsigned short* __restrict__ x16,
                           const int* __restrict__ dst, int* __restrict__ hist,
                           const float* __restrict__ Ws0, const float* __restrict__ Wn0,
                           const float* __restrict__ Ws1, const float* __restrict__ Wn1,
                           const float* __restrict__ Ws2, const float* __restrict__ Wn2,
                           unsigned short* __restrict__ Wf, float* __restrict__ statsg) {
    __shared__ int lh[NBUCK];
    const int bid = blockIdx.x, t = threadIdx.x;

    if (bid < CVT_BLOCKS) {
        int idx = bid * 256 + t;
        float4 v = ((const float4*)x)[idx];
        ushort4 o;
        o.x = f2bf(v.x); o.y = f2bf(v.y); o.z = f2bf(v.z); o.w = f2bf(v.w);
        ((ushort4*)x16)[idx] = o;
    } else if (bid < CVT_BLOCKS + S1_BLOCKS) {
        int blk = bid - CVT_BLOCKS;
        for (int i = t; i < NBUCK; i += 256) lh[i] = 0;
        __syncthreads();
        int e0 = blk * EPB;
        for (int i = 0; i < 13; i++) {
            int k = t + i * 256;
            if (k < EPB) atomicAdd(&lh[dst[e0 + k] >> BSHIFT], 1);
        }
        __syncthreads();
        for (int i = t; i < NBUCK; i += 256) hist[blk * NBUCK + i] = lh[i];
    } else {
        if (bid == CVT_BLOCKS + S1_BLOCKS) {   // zero BN stats: 2 layers x NREP x 256
            for (int i = t; i < 2 * NREP * 256; i += 256) statsg[i] = 0.f;
        }
        // pack weights into MFMA B-fragment order:
        // Wf[layer][kt(8)][nt(8)][lane(64)][j(8)], lane l holds
        // B[kt*32 + 8*(l>>4) + j][nt*16 + (l&15)].
        int idx = (bid - (CVT_BLOCKS + S1_BLOCKS)) * 256 + t;
        if (idx < 3 * 32768) {
            int layer = idx >> 15;
            int rem = idx & 32767;
            int kt = rem >> 12;
            int nt = (rem >> 9) & 7;
            int lane = (rem >> 3) & 63;
            int j = rem & 7;
            int k = kt * 32 + (lane >> 4) * 8 + j;
            int n = nt * 16 + (lane & 15);
            const float* Wsrc;
            if (layer == 0) Wsrc = (k < 128) ? Ws0 : Wn0;
            else if (layer == 1) Wsrc = (k < 128) ? Ws1 : Wn1;
            else Wsrc = (k < 128) ? Ws2 : Wn2;
            Wf[idx] = f2bf(Wsrc[(k & 127) * D + n]);
        }
    }
}

// ---------------- S2a: per-bucket exclusive prefix over blocks ----------------

__global__ void s2a(int* __restrict__ hist, int* __restrict__ bucketTotal) {
    __shared__ int s[S1_BLOCKS];
    int b = blockIdx.x, t = threadIdx.x;
    int v = hist[t * NBUCK + b];
    s[t] = v;
    __syncthreads();
    for (int off = 1; off < S1_BLOCKS; off <<= 1) {
        int x = (t >= off) ? s[t - off] : 0;
        __syncthreads();
        s[t] += x;
        __syncthreads();
    }
    hist[t * NBUCK + b] = s[t] - v;
    if (t == S1_BLOCKS - 1) bucketTotal[b] = s[t];
}

// ---------------- S3: scatter packed records, bucket-grouped ----------------

__global__ void s3_scatter(const int* __restrict__ src, const int* __restrict__ dst,
                           const int* __restrict__ hist, const int* __restrict__ bucketTotal,
                           int* __restrict__ bucketStart, unsigned int* __restrict__ rec) {
    __shared__ int sc[512];
    __shared__ int base[NBUCK];
    int blk = blockIdx.x, t = threadIdx.x;
    int i1 = t + 256;
    int v0 = (t < NBUCK) ? bucketTotal[t] : 0;
    int v1 = (i1 < NBUCK) ? bucketTotal[i1] : 0;
    sc[t] = v0; sc[i1] = v1;
    __syncthreads();
    for (int off = 1; off < 512; off <<= 1) {
        int x0 = (t >= off) ? sc[t - off] : 0;
        int x1 = (i1 >= off) ? sc[i1 - off] : 0;
        __syncthreads();
        sc[t] += x0; sc[i1] += x1;
        __syncthreads();
    }
    if (t < NBUCK)  base[t]  = (sc[t] - v0)  + hist[blk * NBUCK + t];
    if (i1 < NBUCK) base[i1] = (sc[i1] - v1) + hist[blk * NBUCK + i1];
    if (blk == 0) {
        if (t < NBUCK)  bucketStart[t]  = sc[t] - v0;
        if (i1 < NBUCK) bucketStart[i1] = sc[i1] - v1;
        if (t == 0) bucketStart[NBUCK] = N_EDGES;
    }
    __syncthreads();
    int e0 = blk * EPB;
    for (int i = 0; i < 13; i++) {
        int k = t + i * 256;
        if (k < EPB) {
            int e = e0 + k;
            int d = dst[e];
            int p = atomicAdd(&base[d >> BSHIFT], 1);
            rec[p] = ((unsigned)(d & 127) << 16) | (unsigned)src[e];
        }
    }
}

// ---------------- S4: per-bucket counting sort -> CSR + degrees ----------------
// Slice key = (dst&127, src>>12): 1 MB src slices. 2048-bin LDS counting sort.

__global__ void s4_build(const unsigned int* __restrict__ rec, const int* __restrict__ bucketStart,
                         unsigned short* __restrict__ csr, int* __restrict__ degi,
                         int* __restrict__ offsets, float* __restrict__ inv_deg) {
    __shared__ int cnt[128 * NSLICE];
    __shared__ int exc[128 * NSLICE];
    __shared__ int lcur[128 * NSLICE];
    __shared__ int ls[256];
    int b = blockIdx.x, t = threadIdx.x;
    int start = bucketStart[b], end = bucketStart[b + 1];

    for (int i = t; i < 128 * NSLICE; i += 256) cnt[i] = 0;
    __syncthreads();
    for (int e = start + t; e < end; e += 256) {
        unsigned r = rec[e];
        int key = ((r >> 16) << 4) | ((r & 0xFFFFu) >> SSHIFT);
        atomicAdd(&cnt[key], 1);
    }
    __syncthreads();

    // 2048-bin exclusive scan: 8 bins/thread (registers, fully unrolled)
    int cs[8];
    int sum8 = 0;
#pragma unroll
    for (int j = 0; j < 8; j++) { cs[j] = cnt[8 * t + j]; sum8 += cs[j]; }
    ls[t] = sum8;
    __syncthreads();
    for (int off = 1; off < 256; off <<= 1) {
        int x = (t >= off) ? ls[t - off] : 0;
        __syncthreads();
        ls[t] += x;
        __syncthreads();
    }
    int run = ls[t] - sum8;
#pragma unroll
    for (int j = 0; j < 8; j++) {
        exc[8 * t + j] = run;
        lcur[8 * t + j] = start + run;
        run += cs[j];
    }
    __syncthreads();

    if (t < 128) {
        int node = (b << BSHIFT) + t;
        int e0 = exc[t * NSLICE];
        int e1 = (t == 127) ? (end - start) : exc[(t + 1) * NSLICE];
        int v = e1 - e0;
        if (node < N_NODES) {
            degi[node] = v;
            offsets[node] = start + e0;
            inv_deg[node] = 1.0f / (float)max(v, 1);
        }
    }
    __syncthreads();
    for (int e = start + t; e < end; e += 256) {
        unsigned r = rec[e];
        int key = ((r >> 16) << 4) | ((r & 0xFFFFu) >> SSHIFT);
        int p = atomicAdd(&lcur[key], 1);
        csr[p] = (unsigned short)(r & 0xFFFFu);
    }
}

// ---------------- mean aggregation with optional fused BN+ReLU ----------------
// Per-block BN fold into LDS then 16 regs/lane; batched csr indices broadcast
// via __shfl (no per-edge index hop); 4-deep row-gather pipeline.

#define GROW(r) (*(const uint4*)(hb + ((size_t)(r) << 7)))
#define ROWIDX(k) __shfl((int)((k) < 16 ? cb0 : ((k) < 32 ? cb1 : cb2)), (k) & 15, 16)

__global__ void aggregate16(const unsigned short* __restrict__ h16,
                            const unsigned short* __restrict__ csr, const int* __restrict__ offsets,
                            const int* __restrict__ degi, const float* __restrict__ inv_deg,
                            unsigned short* __restrict__ mean16,
                            const float* __restrict__ statsIn,
                            const float* __restrict__ gammaIn, const float* __restrict__ betaIn) {
    __shared__ float lsc[128], lsh[128];
    int t = threadIdx.x;
    if (statsIn) {
        if (t < 128) {
            const float invN = 1.0f / (float)N_NODES;
            float s = 0.f, q = 0.f;
#pragma unroll
            for (int r = 0; r < NREP; r++) {
                s += statsIn[r * 256 + t];
                q += statsIn[r * 256 + 128 + t];
            }
            float m = s * invN;
            float var = q * invN - m * m;
            float scv = rsqrtf(var + BN_EPS) * gammaIn[t];
            lsc[t] = scv;
            lsh[t] = betaIn[t] - m * scv;
        }
        __syncthreads();
    }

    int node = blockIdx.x * 16 + (t >> 4);   // grid*16 == N_NODES exactly
    int c = t & 15;
    const unsigned short* hb = h16 + c * 8;
    int beg = offsets[node], n = degi[node];

    // batch-load up to 48 neighbor indices (lane c holds entries c, 16+c, 32+c)
    int ci = beg + c;
    int cmax = N_EDGES - 1;
    unsigned cb0 = csr[min(ci, cmax)];
    unsigned cb1 = csr[min(ci + 16, cmax)];
    unsigned cb2 = csr[min(ci + 32, cmax)];

    f32x2 a[4];
#pragma unroll
    for (int j = 0; j < 4; j++) a[j] = (f32x2)(0.f);

    int nfast = n < 48 ? n : 48;
    int i = 0;
    if (statsIn) {
        float scv[8], shv[8];
#pragma unroll
        for (int j = 0; j < 8; j++) { scv[j] = lsc[c * 8 + j]; shv[j] = lsh[c * 8 + j]; }
        if (nfast >= 4) {
            uint4 v0 = GROW(ROWIDX(0)), v1 = GROW(ROWIDX(1));
            uint4 v2 = GROW(ROWIDX(2)), v3 = GROW(ROWIDX(3));
            for (i = 4; i + 3 < nfast; i += 4) {
                int r0 = ROWIDX(i), r1 = ROWIDX(i + 1), r2 = ROWIDX(i + 2), r3 = ROWIDX(i + 3);
                uint4 w0 = GROW(r0), w1 = GROW(r1), w2 = GROW(r2), w3 = GROW(r3);
                acc_bn(a, v0, scv, shv); acc_bn(a, v1, scv, shv);
                acc_bn(a, v2, scv, shv); acc_bn(a, v3, scv, shv);
                v0 = w0; v1 = w1; v2 = w2; v3 = w3;
            }
            acc_bn(a, v0, scv, shv); acc_bn(a, v1, scv, shv);
            acc_bn(a, v2, scv, shv); acc_bn(a, v3, scv, shv);
        }
        for (; i < nfast; i++) { uint4 v = GROW(ROWIDX(i)); acc_bn(a, v, scv, shv); }
        for (; i < n; i++) { int r = csr[beg + i]; uint4 v = GROW(r); acc_bn(a, v, scv, shv); }
    } else {
        if (nfast >= 4) {
            uint4 v0 = GROW(ROWIDX(0)), v1 = GROW(ROWIDX(1));
            uint4 v2 = GROW(ROWIDX(2)), v3 = GROW(ROWIDX(3));
            for (i = 4; i + 3 < nfast; i += 4) {
                int r0 = ROWIDX(i), r1 = ROWIDX(i + 1), r2 = ROWIDX(i + 2), r3 = ROWIDX(i + 3);
                uint4 w0 = GROW(r0), w1 = GROW(r1), w2 = GROW(r2), w3 = GROW(r3);
                acc_plain(a, v0); acc_plain(a, v1); acc_plain(a, v2); acc_plain(a, v3);
                v0 = w0; v1 = w1; v2 = w2; v3 = w3;
            }
            acc_plain(a, v0); acc_plain(a, v1); acc_plain(a, v2); acc_plain(a, v3);
        }
        for (; i < nfast; i++) { uint4 v = GROW(ROWIDX(i)); acc_plain(a, v); }
        for (; i < n; i++) { int r = csr[beg + i]; uint4 v = GROW(r); acc_plain(a, v); }
    }

    float w = inv_deg[node];
    uint4 o;
    o.x = ((unsigned)f2bf(a[0].y * w) << 16) | f2bf(a[0].x * w);
    o.y = ((unsigned)f2bf(a[1].y * w) << 16) | f2bf(a[1].x * w);
    o.z = ((unsigned)f2bf(a[2].y * w) << 16) | f2bf(a[2].x * w);
    o.w = ((unsigned)f2bf(a[3].y * w) << 16) | f2bf(a[3].x * w);
    *(uint4*)(mean16 + (size_t)node * D + c * 8) = o;
}

// ---------------- MFMA SAGE GEMM + fused BN col-stats ----------------
// Self A-fragments get BN+ReLU applied in-register (fold via LDS);
// mean16 input is already post-BN-aggregated. Stats scattered across NREP
// replica slots. C/D layout (m89-verified): col = lane&15, row = (lane>>4)*4+reg.

__global__ __launch_bounds__(256, 4) void sage_gemm(
    const unsigned short* __restrict__ h16, const unsigned short* __restrict__ mean16,
    const unsigned short* __restrict__ Wf, const float* __restrict__ bias,
    unsigned short* __restrict__ out16, float* __restrict__ outf,
    float* __restrict__ statsOut,
    const float* __restrict__ statsIn,
    const float* __restrict__ gammaIn, const float* __restrict__ betaIn) {
    __shared__ unsigned short sWf[16384];   // 32 KB: one K-half (4 kt x 8 nt x 64 x 8)
    __shared__ float sstat[256];
    __shared__ float lsc[128], lsh[128];
    const int t = threadIdx.x;
    const int lane = t & 63;
    const int m = lane & 15;
    const int quad = lane >> 4;
    const int wrow0 = blockIdx.x * 64 + (t >> 6) * 16;

    int arow = wrow0 + m;
    if (arow >= N_NODES) arow = N_NODES - 1;

    // prefetch all 8 A-fragments (4 self + 4 mean) into registers
    bf16x8 afr[8];
#pragma unroll
    for (int kt = 0; kt < 4; kt++)
        afr[kt] = *(const bf16x8*)(h16 + (size_t)arow * D + kt * 32 + quad * 8);
#pragma unroll
    for (int kt = 0; kt < 4; kt++)
        afr[4 + kt] = *(const bf16x8*)(mean16 + (size_t)arow * D + kt * 32 + quad * 8);

    // fold BN table for self fragments (layers 1,2)
    if (statsIn && t < 128) {
        const float invN = 1.0f / (float)N_NODES;
        float s = 0.f, q = 0.f;
#pragma unroll
        for (int r = 0; r < NREP; r++) {
            s += statsIn[r * 256 + t];
            q += statsIn[r * 256 + 128 + t];
        }
        float m2 = s * invN;
        float var = q * invN - m2 * m2;
        float scv = rsqrtf(var + BN_EPS) * gammaIn[t];
        lsc[t] = scv;
        lsh[t] = betaIn[t] - m2 * scv;
    }

    // stage first weight half (kt 0-3)
    const uint4* W4 = (const uint4*)Wf;
    uint4* S4 = (uint4*)sWf;
#pragma unroll
    for (int i = 0; i < 8; i++) S4[i * 256 + t] = W4[i * 256 + t];
    if (statsOut) sstat[t] = 0.f;
    __syncthreads();

    // apply BN+ReLU to self fragments in-register
    if (statsIn) {
#pragma unroll
        for (int kt = 0; kt < 4; kt++) {
            int c0 = kt * 32 + quad * 8;
#pragma unroll
            for (int j = 0; j < 8; j++) {
                float v = fmaxf(bf2f((unsigned short)afr[kt][j]) * lsc[c0 + j] + lsh[c0 + j], 0.f);
                afr[kt][j] = (short)f2bf(v);
            }
        }
    }

    f32x4 acc[8];
#pragma unroll
    for (int i = 0; i < 8; i++) acc[i] = (f32x4)(0.f);

#pragma unroll
    for (int kt = 0; kt < 4; kt++) {
#pragma unroll
        for (int nt = 0; nt < 8; nt++) {
            bf16x8 bf = *(const bf16x8*)(sWf + ((kt * 8 + nt) * 64 + lane) * 8);
            acc[nt] = __builtin_amdgcn_mfma_f32_16x16x32_bf16(afr[kt], bf, acc[nt], 0, 0, 0);
        }
    }

    __syncthreads();   // all waves done with half 1 before overwrite
#pragma unroll
    for (int i = 0; i < 8; i++) S4[i * 256 + t] = W4[2048 + i * 256 + t];
    __syncthreads();

#pragma unroll
    for (int kt = 4; kt < 8; kt++) {
#pragma unroll
        for (int nt = 0; nt < 8; nt++) {
            bf16x8 bf = *(const bf16x8*)(sWf + (((kt - 4) * 8 + nt) * 64 + lane) * 8);
            acc[nt] = __builtin_amdgcn_mfma_f32_16x16x32_bf16(afr[kt], bf, acc[nt], 0, 0, 0);
        }
    }

    const bool do16 = (out16 != nullptr);
#pragma unroll
    for (int nt = 0; nt < 8; nt++) {
        int cidx = nt * 16 + m;
        float bv = bias[cidx];
        float s = 0.f, q = 0.f;
#pragma unroll
        for (int reg = 0; reg < 4; reg++) {
            int r = wrow0 + quad * 4 + reg;
            float v = acc[nt][reg] + bv;
            if (r < N_NODES) {
                if (do16) out16[(size_t)r * D + cidx] = f2bf(v);
                else      outf[(size_t)r * D + cidx] = v;
                s += v; q += v * v;
            }
        }
        if (statsOut) {
            s += __shfl_xor(s, 16); s += __shfl_xor(s, 32);
            q += __shfl_xor(q, 16); q += __shfl_xor(q, 32);
            if (quad == 0) {
                atomicAdd(&sstat[cidx], s);
                atomicAdd(&sstat[128 + cidx], q);
            }
        }
    }
    if (statsOut) {
        __syncthreads();
        atomicAdd(&statsOut[(blockIdx.x & (NREP - 1)) * 256 + t], sstat[t]);
    }
}

// ---------------- launch ----------------

extern "C" void kernel_launch(void* const* d_in, const int* in_sizes, int n_in,
                              void* d_out, int out_size, void* d_ws, size_t ws_size,
                              hipStream_t stream) {
    const float* x   = (const float*)d_in[0];
    const int* src   = (const int*)d_in[1];
    const int* dst   = (const int*)d_in[2];
    const float* Ws0 = (const float*)d_in[3];
    const float* Wn0 = (const float*)d_in[4];
    const float* b0  = (const float*)d_in[5];
    const float* Ws1 = (const float*)d_in[6];
    const float* Wn1 = (const float*)d_in[7];
    const float* b1  = (const float*)d_in[8];
    const float* Ws2 = (const float*)d_in[9];
    const float* Wn2 = (const float*)d_in[10];
    const float* b2  = (const float*)d_in[11];
    const float* g0  = (const float*)d_in[12];
    const float* be0 = (const float*)d_in[13];
    const float* g1  = (const float*)d_in[14];
    const float* be1 = (const float*)d_in[15];

    char* base = (char*)d_ws;
    size_t NND = (size_t)N_NODES * D;
    unsigned short* X16    = (unsigned short*)base;                 // 12.8 MB
    unsigned short* H16    = (unsigned short*)(base + NND * 2);     // 12.8 MB
    unsigned short* mean16 = (unsigned short*)(base + 2 * NND * 2); // 12.8 MB
    char* p = base + 6 * NND;
    unsigned short* Wf = (unsigned short*)p;  p += 3 * 32768 * 2;                  // 192 KB
    int* hist          = (int*)p;             p += (size_t)S1_BLOCKS * NBUCK * 4;  // 400 KB
    int* bucketTotal   = (int*)p;             p += 1568;
    int* bucketStart   = (int*)p;             p += 1600;
    unsigned int* rec  = (unsigned int*)p;    p += (size_t)N_EDGES * 4;            // 3.2 MB
    unsigned short* csr = (unsigned short*)p; p += (size_t)N_EDGES * 2;            // 1.6 MB
    int* degi    = (int*)p;                   p += N_NODES * 4;
    int* offsets = (int*)p;                   p += N_NODES * 4;
    float* inv_deg = (float*)p;               p += N_NODES * 4;
    float* stats   = (float*)p;               p += 2 * NREP * 256 * 4;  // replicated
    float* stats0 = stats, *stats1 = stats + NREP * 256;

    // prep: feature convert + edge histogram + weight pack + zero stats
    fused_prep<<<CVT_BLOCKS + S1_BLOCKS + PACK_BLOCKS, 256, 0, stream>>>(
        x, X16, dst, hist, Ws0, Wn0, Ws1, Wn1, Ws2, Wn2, Wf, stats);
    // CSR build: 3 kernels (s2b folded into s3 as redundant per-block scan)
    s2a<<<NBUCK, 256, 0, stream>>>(hist, bucketTotal);
    s3_scatter<<<S1_BLOCKS, 256, 0, stream>>>(src, dst, hist, bucketTotal, bucketStart, rec);
    s4_build<<<NBUCK, 256, 0, stream>>>(rec, bucketStart, csr, degi, offsets, inv_deg);

    const int AGG_B = (N_NODES + 15) / 16;   // 3125
    const int GEMM_B = (N_NODES + 63) / 64;  // 782

    // Layer 0: X16 (no BN) -> H16 raw + stats0
    aggregate16<<<AGG_B, 256, 0, stream>>>(X16, csr, offsets, degi, inv_deg, mean16,
                                           nullptr, nullptr, nullptr);
    sage_gemm<<<GEMM_B, 256, 0, stream>>>(X16, mean16, Wf, b0, H16, nullptr,
                                          stats0, nullptr, nullptr, nullptr);

    // Layer 1: consumers apply bn0+relu to H16 raw -> X16 raw + stats1
    aggregate16<<<AGG_B, 256, 0, stream>>>(H16, csr, offsets, degi, inv_deg, mean16,
                                           stats0, g0, be0);
    sage_gemm<<<GEMM_B, 256, 0, stream>>>(H16, mean16, Wf + 32768, b1, X16, nullptr,
                                          stats1, stats0, g0, be0);

    // Layer 2: consumers apply bn1+relu to X16 raw -> d_out fp32
    aggregate16<<<AGG_B, 256, 0, stream>>>(X16, csr, offsets, degi, inv_deg, mean16,
                                           stats1, g1, be1);
    sage_gemm<<<GEMM_B, 256, 0, stream>>>(X16, mean16, Wf + 65536, b2, nullptr,
                                          (float*)d_out, nullptr, stats1, g1, be1);
}